// Round 1
// 844.347 us; speedup vs baseline: 1.0070x; 1.0070x over previous
//
#include <hip/hip_runtime.h>
#include <hip/hip_bf16.h>

// Round 8: swapped-QK^T flash attention (lane-local softmax rows), KVBLK=64,
// no block barriers (P round-trip is wave-private), setprio around MFMA.
// GEMM/transpose stages unchanged from R7.

#define S_LEN 2048

typedef __hip_bfloat16 bf16;
using bf16x8 = __attribute__((ext_vector_type(8))) __bf16;
using f32x4  = __attribute__((ext_vector_type(4))) float;

__device__ inline unsigned short bf16_bits(float f) {
    union { __hip_bfloat16 h; unsigned short u; } cv;
    cv.h = __float2bfloat16(f);
    return cv.u;
}

// load 8 consecutive fp32, convert RNE to a bf16x8 fragment
__device__ inline bf16x8 load_cvt8(const float* __restrict__ p) {
    f32x4 a = *(const f32x4*)p;
    f32x4 b = *(const f32x4*)(p + 4);
    union { bf16x8 v; unsigned short u[8]; } r;
    r.u[0] = bf16_bits(a[0]); r.u[1] = bf16_bits(a[1]);
    r.u[2] = bf16_bits(a[2]); r.u[3] = bf16_bits(a[3]);
    r.u[4] = bf16_bits(b[0]); r.u[5] = bf16_bits(b[1]);
    r.u[6] = bf16_bits(b[2]); r.u[7] = bf16_bits(b[3]);
    return r.v;
}

// ---------------- weight transpose + fp32->bf16: out[n][k] = (bf16)in[k][n] ----
__global__ __launch_bounds__(256) void transpose_k(const float* __restrict__ in,
                                                   bf16* __restrict__ out,
                                                   int R, int C) {
    __shared__ float tile[32][33];
    int tx = threadIdx.x & 31, ty = threadIdx.x >> 5;  // ty 0..7
    int r0 = blockIdx.y * 32, c0 = blockIdx.x * 32;
#pragma unroll
    for (int p = 0; p < 4; ++p)
        tile[ty + p * 8][tx] = in[(size_t)(r0 + ty + p * 8) * C + c0 + tx];
    __syncthreads();
#pragma unroll
    for (int p = 0; p < 4; ++p)
        out[(size_t)(c0 + ty + p * 8) * R + r0 + tx] = __float2bfloat16(tile[tx][ty + p * 8]);
}

// ---------------- GEMM: C = A[M,K] * Bt[N,K]^T (bf16 MFMA, fp32 acc)
// a_fp32: A is fp32 (converted during LDS staging) else bf16.
// mode 0: bf16 row-major C. mode 1: V-transpose epilogue into Vt[b][hkv][d][s].
// mode 2: fp32 row-major C.
__global__ __launch_bounds__(256) void gemm_k(const void* __restrict__ Av,
                                              const bf16* __restrict__ Bt,
                                              void* __restrict__ Cv,
                                              int M, int N, int K, int mode, int a_fp32) {
    __shared__ bf16 As[128 * 40];
    __shared__ bf16 Bs[128 * 40];
    int tid  = threadIdx.x;
    int lane = tid & 63, wave = tid >> 6;
    int quad = lane >> 4, r = lane & 15;
    int wm = (wave >> 1) * 64, wn = (wave & 1) * 64;
    int m0 = blockIdx.y * 128, n0 = blockIdx.x * 128;

    f32x4 acc[4][4];
#pragma unroll
    for (int i = 0; i < 4; ++i)
#pragma unroll
        for (int j = 0; j < 4; ++j) acc[i][j] = (f32x4)0.0f;

    int srow = tid >> 2;            // 0..63
    int skc  = (tid & 3) << 3;      // 0,8,16,24

    const float* Af = (const float*)Av;
    const bf16*  Ab = (const bf16*)Av;

    for (int k0 = 0; k0 < K; k0 += 32) {
        __syncthreads();
        if (a_fp32) {
            *(bf16x8*)&As[srow * 40 + skc]        = load_cvt8(Af + (size_t)(m0 + srow) * K + k0 + skc);
            *(bf16x8*)&As[(srow + 64) * 40 + skc] = load_cvt8(Af + (size_t)(m0 + srow + 64) * K + k0 + skc);
        } else {
            *(bf16x8*)&As[srow * 40 + skc]        = *(const bf16x8*)(Ab + (size_t)(m0 + srow) * K + k0 + skc);
            *(bf16x8*)&As[(srow + 64) * 40 + skc] = *(const bf16x8*)(Ab + (size_t)(m0 + srow + 64) * K + k0 + skc);
        }
        *(bf16x8*)&Bs[srow * 40 + skc]        = *(const bf16x8*)(Bt + (size_t)(n0 + srow) * K + k0 + skc);
        *(bf16x8*)&Bs[(srow + 64) * 40 + skc] = *(const bf16x8*)(Bt + (size_t)(n0 + srow + 64) * K + k0 + skc);
        __syncthreads();
        bf16x8 af[4], bfr[4];
#pragma unroll
        for (int mt = 0; mt < 4; ++mt) af[mt]  = *(const bf16x8*)&As[(wm + mt * 16 + r) * 40 + quad * 8];
#pragma unroll
        for (int nt = 0; nt < 4; ++nt) bfr[nt] = *(const bf16x8*)&Bs[(wn + nt * 16 + r) * 40 + quad * 8];
#pragma unroll
        for (int mt = 0; mt < 4; ++mt)
#pragma unroll
            for (int nt = 0; nt < 4; ++nt)
                acc[mt][nt] = __builtin_amdgcn_mfma_f32_16x16x32_bf16(af[mt], bfr[nt], acc[mt][nt], 0, 0, 0);
    }

    if (mode == 0) {
        bf16* C = (bf16*)Cv;
#pragma unroll
        for (int mt = 0; mt < 4; ++mt)
#pragma unroll
            for (int nt = 0; nt < 4; ++nt) {
                int row = m0 + wm + mt * 16 + quad * 4;
                int col = n0 + wn + nt * 16 + r;
#pragma unroll
                for (int i = 0; i < 4; ++i)
                    C[(size_t)(row + i) * N + col] = __float2bfloat16(acc[mt][nt][i]);
            }
    } else if (mode == 1) {
        // Vt[b][hkv][d][s]: flat = (b*512 + col)*2048 + s ; 4 consecutive tokens per lane
        unsigned short* C = (unsigned short*)Cv;
#pragma unroll
        for (int mt = 0; mt < 4; ++mt)
#pragma unroll
            for (int nt = 0; nt < 4; ++nt) {
                int rowb = m0 + wm + mt * 16 + quad * 4;
                int col  = n0 + wn + nt * 16 + r;
                int b = rowb >> 11, s = rowb & 2047;
                ushort4 pk;
                pk.x = bf16_bits(acc[mt][nt][0]);
                pk.y = bf16_bits(acc[mt][nt][1]);
                pk.z = bf16_bits(acc[mt][nt][2]);
                pk.w = bf16_bits(acc[mt][nt][3]);
                *(ushort4*)(C + (size_t)(b * 512 + col) * 2048 + s) = pk;
            }
    } else {
        float* C = (float*)Cv;
#pragma unroll
        for (int mt = 0; mt < 4; ++mt)
#pragma unroll
            for (int nt = 0; nt < 4; ++nt) {
                int row = m0 + wm + mt * 16 + quad * 4;
                int col = n0 + wn + nt * 16 + r;
#pragma unroll
                for (int i = 0; i < 4; ++i)
                    C[(size_t)(row + i) * N + col] = acc[mt][nt][i];
            }
    }
}

// ---------------- flash attention (GQA), one (b, h, 64-row q-tile) per block
// Swapped QK^T: St = mfma(K, Q) -> lane owns q = lane&15, kv over regs/quads.
// Softmax row-reduce: 15 in-lane ops + 2 shuffles. No block barriers.
// Qin: [B,S,2048] bf16 (h*64+d), K: [B,S,512] bf16, Vt: [B][8][64][S] bf16
// Aout: [B,S,2048] bf16
__global__ __launch_bounds__(256) void attn_k(const bf16* __restrict__ Qin,
                                              const bf16* __restrict__ Kb,
                                              const bf16* __restrict__ Vt,
                                              bf16* __restrict__ Aout) {
    __shared__ bf16 Pl[4][16 * 72];   // wave-private P round-trip (St layout -> A layout)
    int tid = threadIdx.x, lane = tid & 63, w = tid >> 6;
    int quad = lane >> 4, r = lane & 15;
    int qt = blockIdx.x, h = blockIdx.y, b = blockIdx.z;
    int hk = h >> 2;
    int q0 = qt * 64 + w * 16;

    bf16x8 qf[2];
#pragma unroll
    for (int f = 0; f < 2; ++f)
        qf[f] = *(const bf16x8*)(Qin + (size_t)(b * S_LEN + q0 + r) * 2048 + h * 64 + f * 32 + quad * 8);

    const bf16* Kbase = Kb + (size_t)b * S_LEN * 512 + hk * 64;
    const bf16* Vbase = Vt + (size_t)(b * 512 + hk * 64) * 2048;
    bf16* myP = &Pl[w][0];

    f32x4 oacc[4];
#pragma unroll
    for (int dt = 0; dt < 4; ++dt) oacc[dt] = (f32x4)0.0f;
    float m_r = -INFINITY, l_r = 0.0f;   // per-lane state for q = r (dup across quads)

    for (int k0 = 0; k0 < S_LEN; k0 += 64) {
        // issue all global loads up front; latency hides under QK + softmax
        bf16x8 kf[4][2], vf[4][2];
#pragma unroll
        for (int t = 0; t < 4; ++t) {
            kf[t][0] = *(const bf16x8*)(Kbase + (size_t)(k0 + t * 16 + r) * 512 + quad * 8);
            kf[t][1] = *(const bf16x8*)(Kbase + (size_t)(k0 + t * 16 + r) * 512 + 32 + quad * 8);
        }
#pragma unroll
        for (int dt = 0; dt < 4; ++dt) {
            vf[dt][0] = *(const bf16x8*)(Vbase + (size_t)(dt * 16 + r) * 2048 + k0 + quad * 8);
            vf[dt][1] = *(const bf16x8*)(Vbase + (size_t)(dt * 16 + r) * 2048 + k0 + 32 + quad * 8);
        }

        // QK^T swapped: St[t] = S^T[kv = k0+t*16+quad*4+i][q = q0+r]
        f32x4 St[4];
        __builtin_amdgcn_s_setprio(1);
#pragma unroll
        for (int t = 0; t < 4; ++t) {
            St[t] = (f32x4)0.0f;
            St[t] = __builtin_amdgcn_mfma_f32_16x16x32_bf16(kf[t][0], qf[0], St[t], 0, 0, 0);
            St[t] = __builtin_amdgcn_mfma_f32_16x16x32_bf16(kf[t][1], qf[1], St[t], 0, 0, 0);
        }
        __builtin_amdgcn_s_setprio(0);

        // online softmax: 16 kv values in-lane, reduce over quads with 2 shuffles
        float tv[16];
#pragma unroll
        for (int t = 0; t < 4; ++t)
#pragma unroll
            for (int i = 0; i < 4; ++i) tv[t * 4 + i] = St[t][i] * 0.125f;
        float mt = tv[0];
#pragma unroll
        for (int j = 1; j < 16; ++j) mt = fmaxf(mt, tv[j]);
        mt = fmaxf(mt, __shfl_xor(mt, 16));
        mt = fmaxf(mt, __shfl_xor(mt, 32));
        float mnew = fmaxf(m_r, mt);
        float p[16], rs = 0.0f;
#pragma unroll
        for (int j = 0; j < 16; ++j) { p[j] = __expf(tv[j] - mnew); rs += p[j]; }
        rs += __shfl_xor(rs, 16);
        rs += __shfl_xor(rs, 32);
        float alpha = __expf(m_r - mnew);
        l_r = l_r * alpha + rs;
        m_r = mnew;

        // P -> LDS (wave-private, no barrier): row q=r, col kv = t*16 + quad*4 + i
#pragma unroll
        for (int t = 0; t < 4; ++t) {
            union { unsigned long long u; unsigned short s[4]; } pk;
#pragma unroll
            for (int i = 0; i < 4; ++i) pk.s[i] = bf16_bits(p[t * 4 + i]);
            *(unsigned long long*)&myP[r * 72 + t * 16 + quad * 4] = pk.u;
        }
        bf16x8 pf0 = *(const bf16x8*)&myP[r * 72 + quad * 8];
        bf16x8 pf1 = *(const bf16x8*)&myP[r * 72 + 32 + quad * 8];

        // alpha for oacc rows q = quad*4+i lives in lane quad*4+i
        float ab[4];
#pragma unroll
        for (int i = 0; i < 4; ++i) ab[i] = __shfl(alpha, quad * 4 + i);

        __builtin_amdgcn_s_setprio(1);
#pragma unroll
        for (int dt = 0; dt < 4; ++dt) {
            f32x4 o = oacc[dt];
#pragma unroll
            for (int i = 0; i < 4; ++i) o[i] *= ab[i];
            o = __builtin_amdgcn_mfma_f32_16x16x32_bf16(pf0, vf[dt][0], o, 0, 0, 0);
            o = __builtin_amdgcn_mfma_f32_16x16x32_bf16(pf1, vf[dt][1], o, 0, 0, 0);
            oacc[dt] = o;
        }
        __builtin_amdgcn_s_setprio(0);
    }

    float linv[4];
#pragma unroll
    for (int i = 0; i < 4; ++i) linv[i] = 1.0f / __shfl(l_r, quad * 4 + i);
#pragma unroll
    for (int dt = 0; dt < 4; ++dt)
#pragma unroll
        for (int i = 0; i < 4; ++i)
            Aout[(size_t)(b * S_LEN + q0 + quad * 4 + i) * 2048 + h * 64 + dt * 16 + r] =
                __float2bfloat16(oacc[dt][i] * linv[i]);
}

extern "C" void kernel_launch(void* const* d_in, const int* in_sizes, int n_in,
                              void* d_out, int out_size, void* d_ws, size_t ws_size,
                              hipStream_t stream) {
    const float* x  = (const float*)d_in[0];
    const float* wq = (const float*)d_in[1];
    const float* wk = (const float*)d_in[2];
    const float* wv = (const float*)d_in[3];
    const float* wo = (const float*)d_in[4];
    char* ws = (char*)d_ws;

    // d_out is 32 MB fp32. Park bf16 Q (16 MB) in its first half; the final
    // GEMM overwrites all of d_out with fp32 results afterwards.
    // ws (24 MB, phased):
    //   phase 1: [0,8M)=wqT [8,10M)=wkT [10,12M)=wvT
    //   phase 2: [0,16M)=attnOut(bf16)  [16,20M)=Kb  [20,24M)=Vt
    //   phase 3: [0,16M)=attnOut        [16,24M)=woT
    bf16* wqT  = (bf16*)(ws + 0);
    bf16* wkT  = (bf16*)(ws + 8388608);
    bf16* wvT  = (bf16*)(ws + 10485760);
    bf16* attn = (bf16*)(ws + 0);
    bf16* Kb   = (bf16*)(ws + 16777216);
    bf16* Vtb  = (bf16*)(ws + 20971520);
    bf16* woT  = (bf16*)(ws + 16777216);
    bf16* Qb   = (bf16*)d_out;

    transpose_k<<<dim3(64, 64), 256, 0, stream>>>(wq, wqT, 2048, 2048);
    transpose_k<<<dim3(16, 64), 256, 0, stream>>>(wk, wkT, 2048, 512);
    transpose_k<<<dim3(16, 64), 256, 0, stream>>>(wv, wvT, 2048, 512);

    gemm_k<<<dim3(16, 32), 256, 0, stream>>>(x, wqT, Qb, 4096, 2048, 2048, 0, 1);
    gemm_k<<<dim3(4, 32), 256, 0, stream>>>(x, wkT, Kb, 4096, 512, 2048, 0, 1);
    gemm_k<<<dim3(4, 32), 256, 0, stream>>>(x, wvT, Vtb, 4096, 512, 2048, 1, 1);

    attn_k<<<dim3(32, 32, 2), 256, 0, stream>>>(Qb, Kb, Vtb, attn);

    // Kb/Vt dead; put woT in their slot
    transpose_k<<<dim3(64, 64), 256, 0, stream>>>(wo, woT, 2048, 2048);

    // fp32 epilogue into d_out
    gemm_k<<<dim3(16, 32), 256, 0, stream>>>(attn, woT, d_out, 4096, 2048, 2048, 2, 0);
}

// Round 2
// 541.477 us; speedup vs baseline: 1.5702x; 1.5593x over previous
//
#include <hip/hip_runtime.h>
#include <hip/hip_bf16.h>

// Round 9: attn_k rebuilt as LDS-staged double-buffered flash attention.
// K/V staged via global_load_lds (async DMA, no VGPR round trip) with
// XOR-chunk swizzle (T21: linear dest + inverse-swizzled source + swizzled
// read). Swapped-QK^T lane-local softmax kept from R8. Q pre-scaled by 1/8.
// GEMM/transpose stages unchanged.

#define S_LEN 2048

typedef __hip_bfloat16 bf16;
using bf16x8 = __attribute__((ext_vector_type(8))) __bf16;
using f32x4  = __attribute__((ext_vector_type(4))) float;

__device__ inline unsigned short bf16_bits(float f) {
    union { __hip_bfloat16 h; unsigned short u; } cv;
    cv.h = __float2bfloat16(f);
    return cv.u;
}

__device__ inline float bits_to_f(unsigned short u) {
    union { __hip_bfloat16 h; unsigned short u; } cv;
    cv.u = u;
    return __bfloat162float(cv.h);
}

// load 8 consecutive fp32, convert RNE to a bf16x8 fragment
__device__ inline bf16x8 load_cvt8(const float* __restrict__ p) {
    f32x4 a = *(const f32x4*)p;
    f32x4 b = *(const f32x4*)(p + 4);
    union { bf16x8 v; unsigned short u[8]; } r;
    r.u[0] = bf16_bits(a[0]); r.u[1] = bf16_bits(a[1]);
    r.u[2] = bf16_bits(a[2]); r.u[3] = bf16_bits(a[3]);
    r.u[4] = bf16_bits(b[0]); r.u[5] = bf16_bits(b[1]);
    r.u[6] = bf16_bits(b[2]); r.u[7] = bf16_bits(b[3]);
    return r.v;
}

// async global->LDS, 16B per lane, dest = lptr + lane*16 (wave-uniform base)
__device__ inline void gload_lds16(const bf16* g, bf16* l) {
    __builtin_amdgcn_global_load_lds((const __attribute__((address_space(1))) void*)g,
                                     (__attribute__((address_space(3))) void*)l,
                                     16, 0, 0);
}

// ---------------- weight transpose + fp32->bf16: out[n][k] = (bf16)in[k][n] ----
__global__ __launch_bounds__(256) void transpose_k(const float* __restrict__ in,
                                                   bf16* __restrict__ out,
                                                   int R, int C) {
    __shared__ float tile[32][33];
    int tx = threadIdx.x & 31, ty = threadIdx.x >> 5;  // ty 0..7
    int r0 = blockIdx.y * 32, c0 = blockIdx.x * 32;
#pragma unroll
    for (int p = 0; p < 4; ++p)
        tile[ty + p * 8][tx] = in[(size_t)(r0 + ty + p * 8) * C + c0 + tx];
    __syncthreads();
#pragma unroll
    for (int p = 0; p < 4; ++p)
        out[(size_t)(c0 + ty + p * 8) * R + r0 + tx] = __float2bfloat16(tile[tx][ty + p * 8]);
}

// ---------------- GEMM: C = A[M,K] * Bt[N,K]^T (bf16 MFMA, fp32 acc)
// a_fp32: A is fp32 (converted during LDS staging) else bf16.
// mode 0: bf16 row-major C. mode 1: V-transpose epilogue into Vt[b][hkv][d][s].
// mode 2: fp32 row-major C.
__global__ __launch_bounds__(256) void gemm_k(const void* __restrict__ Av,
                                              const bf16* __restrict__ Bt,
                                              void* __restrict__ Cv,
                                              int M, int N, int K, int mode, int a_fp32) {
    __shared__ bf16 As[128 * 40];
    __shared__ bf16 Bs[128 * 40];
    int tid  = threadIdx.x;
    int lane = tid & 63, wave = tid >> 6;
    int quad = lane >> 4, r = lane & 15;
    int wm = (wave >> 1) * 64, wn = (wave & 1) * 64;
    int m0 = blockIdx.y * 128, n0 = blockIdx.x * 128;

    f32x4 acc[4][4];
#pragma unroll
    for (int i = 0; i < 4; ++i)
#pragma unroll
        for (int j = 0; j < 4; ++j) acc[i][j] = (f32x4)0.0f;

    int srow = tid >> 2;            // 0..63
    int skc  = (tid & 3) << 3;      // 0,8,16,24

    const float* Af = (const float*)Av;
    const bf16*  Ab = (const bf16*)Av;

    for (int k0 = 0; k0 < K; k0 += 32) {
        __syncthreads();
        if (a_fp32) {
            *(bf16x8*)&As[srow * 40 + skc]        = load_cvt8(Af + (size_t)(m0 + srow) * K + k0 + skc);
            *(bf16x8*)&As[(srow + 64) * 40 + skc] = load_cvt8(Af + (size_t)(m0 + srow + 64) * K + k0 + skc);
        } else {
            *(bf16x8*)&As[srow * 40 + skc]        = *(const bf16x8*)(Ab + (size_t)(m0 + srow) * K + k0 + skc);
            *(bf16x8*)&As[(srow + 64) * 40 + skc] = *(const bf16x8*)(Ab + (size_t)(m0 + srow + 64) * K + k0 + skc);
        }
        *(bf16x8*)&Bs[srow * 40 + skc]        = *(const bf16x8*)(Bt + (size_t)(n0 + srow) * K + k0 + skc);
        *(bf16x8*)&Bs[(srow + 64) * 40 + skc] = *(const bf16x8*)(Bt + (size_t)(n0 + srow + 64) * K + k0 + skc);
        __syncthreads();
        bf16x8 af[4], bfr[4];
#pragma unroll
        for (int mt = 0; mt < 4; ++mt) af[mt]  = *(const bf16x8*)&As[(wm + mt * 16 + r) * 40 + quad * 8];
#pragma unroll
        for (int nt = 0; nt < 4; ++nt) bfr[nt] = *(const bf16x8*)&Bs[(wn + nt * 16 + r) * 40 + quad * 8];
#pragma unroll
        for (int mt = 0; mt < 4; ++mt)
#pragma unroll
            for (int nt = 0; nt < 4; ++nt)
                acc[mt][nt] = __builtin_amdgcn_mfma_f32_16x16x32_bf16(af[mt], bfr[nt], acc[mt][nt], 0, 0, 0);
    }

    if (mode == 0) {
        bf16* C = (bf16*)Cv;
#pragma unroll
        for (int mt = 0; mt < 4; ++mt)
#pragma unroll
            for (int nt = 0; nt < 4; ++nt) {
                int row = m0 + wm + mt * 16 + quad * 4;
                int col = n0 + wn + nt * 16 + r;
#pragma unroll
                for (int i = 0; i < 4; ++i)
                    C[(size_t)(row + i) * N + col] = __float2bfloat16(acc[mt][nt][i]);
            }
    } else if (mode == 1) {
        // Vt[b][hkv][d][s]: flat = (b*512 + col)*2048 + s ; 4 consecutive tokens per lane
        unsigned short* C = (unsigned short*)Cv;
#pragma unroll
        for (int mt = 0; mt < 4; ++mt)
#pragma unroll
            for (int nt = 0; nt < 4; ++nt) {
                int rowb = m0 + wm + mt * 16 + quad * 4;
                int col  = n0 + wn + nt * 16 + r;
                int b = rowb >> 11, s = rowb & 2047;
                ushort4 pk;
                pk.x = bf16_bits(acc[mt][nt][0]);
                pk.y = bf16_bits(acc[mt][nt][1]);
                pk.z = bf16_bits(acc[mt][nt][2]);
                pk.w = bf16_bits(acc[mt][nt][3]);
                *(ushort4*)(C + (size_t)(b * 512 + col) * 2048 + s) = pk;
            }
    } else {
        float* C = (float*)Cv;
#pragma unroll
        for (int mt = 0; mt < 4; ++mt)
#pragma unroll
            for (int nt = 0; nt < 4; ++nt) {
                int row = m0 + wm + mt * 16 + quad * 4;
                int col = n0 + wn + nt * 16 + r;
#pragma unroll
                for (int i = 0; i < 4; ++i)
                    C[(size_t)(row + i) * N + col] = acc[mt][nt][i];
            }
    }
}

// ---------------- flash attention (GQA), one (b, h, 64-row q-tile) per block
// LDS-staged K/V (double-buffered, global_load_lds DMA, XOR-chunk swizzle).
// Swapped QK^T: St = mfma(K, Q) -> lane owns q = lane&15, kv over regs/quads.
// Qin: [B,S,2048] bf16 (h*64+d), K: [B,S,512] bf16, Vt: [B][8][64][S] bf16
// Aout: [B,S,2048] bf16
__global__ __launch_bounds__(256) void attn_k(const bf16* __restrict__ Qin,
                                              const bf16* __restrict__ Kb,
                                              const bf16* __restrict__ Vt,
                                              bf16* __restrict__ Aout) {
    __shared__ bf16 Ks[2][64 * 64];   // [kv local][d], 16B chunks XOR-swizzled by row&7
    __shared__ bf16 Vs[2][64 * 64];   // [d][kv local], same swizzle
    __shared__ bf16 Pl[4][16 * 72];   // wave-private P round-trip

    int tid = threadIdx.x, lane = tid & 63, w = tid >> 6;
    int quad = lane >> 4, r = lane & 15;
    int qt = blockIdx.x, h = blockIdx.y, b = blockIdx.z;
    int hk = h >> 2;
    int q0 = qt * 64 + w * 16;

    // Q fragments, pre-scaled by 1/sqrt(64)=0.125 (exact in bf16)
    bf16x8 qf[2];
#pragma unroll
    for (int f = 0; f < 2; ++f) {
        bf16x8 v = *(const bf16x8*)(Qin + (size_t)(b * S_LEN + q0 + r) * 2048 + h * 64 + f * 32 + quad * 8);
        union { bf16x8 v; unsigned short u[8]; } in_, out_;
        in_.v = v;
#pragma unroll
        for (int j = 0; j < 8; ++j) out_.u[j] = bf16_bits(bits_to_f(in_.u[j]) * 0.125f);
        qf[f] = out_.v;
    }

    const bf16* Kbase = Kb + (size_t)b * S_LEN * 512 + hk * 64;
    const bf16* Vbase = Vt + (size_t)(b * 512 + hk * 64) * 2048;
    bf16* myP = &Pl[w][0];

    // staging geometry: each wave stages 16 K-rows and 16 V-rows (2+2 DMA ops)
    int srow   = lane >> 3;              // 0..7 row within 8-row group
    int schunk = (lane & 7) ^ srow;      // inverse-swizzled source chunk

    f32x4 oacc[4];
#pragma unroll
    for (int dt = 0; dt < 4; ++dt) oacc[dt] = (f32x4)0.0f;
    float m_r = -INFINITY, l_r = 0.0f;   // per-lane state for q = r (dup across quads)

    // prologue: stage tile 0
#pragma unroll
    for (int j = 0; j < 2; ++j) {
        int row = w * 16 + j * 8;
        gload_lds16(Kbase + (size_t)(row + srow) * 512 + schunk * 8, &Ks[0][row * 64]);
        gload_lds16(Vbase + (size_t)(row + srow) * 2048 + 0 + schunk * 8, &Vs[0][row * 64]);
    }
    __syncthreads();   // drains vmcnt + barrier

    for (int it = 0; it < S_LEN / 64; ++it) {
        int buf = it & 1;
        int k0n = (it + 1) * 64;
        if (k0n < S_LEN) {
#pragma unroll
            for (int j = 0; j < 2; ++j) {
                int row = w * 16 + j * 8;
                gload_lds16(Kbase + (size_t)(k0n + row + srow) * 512 + schunk * 8, &Ks[buf ^ 1][row * 64]);
                gload_lds16(Vbase + (size_t)(row + srow) * 2048 + k0n + schunk * 8, &Vs[buf ^ 1][row * 64]);
            }
        }

        // K fragments from LDS (swizzled read)
        bf16x8 kf[4][2];
#pragma unroll
        for (int t = 0; t < 4; ++t)
#pragma unroll
            for (int half = 0; half < 2; ++half)
                kf[t][half] = *(const bf16x8*)&Ks[buf][(t * 16 + r) * 64 + ((half * 4 + quad) ^ (r & 7)) * 8];

        f32x4 St[4];
        __builtin_amdgcn_s_setprio(1);
#pragma unroll
        for (int t = 0; t < 4; ++t) {
            St[t] = (f32x4)0.0f;
            St[t] = __builtin_amdgcn_mfma_f32_16x16x32_bf16(kf[t][0], qf[0], St[t], 0, 0, 0);
            St[t] = __builtin_amdgcn_mfma_f32_16x16x32_bf16(kf[t][1], qf[1], St[t], 0, 0, 0);
        }
        __builtin_amdgcn_s_setprio(0);

        // online softmax (Q pre-scaled): 16 kv values in-lane, 2 shuffles over quads
        float tv[16];
#pragma unroll
        for (int t = 0; t < 4; ++t)
#pragma unroll
            for (int i = 0; i < 4; ++i) tv[t * 4 + i] = St[t][i];
        float mt = tv[0];
#pragma unroll
        for (int j = 1; j < 16; ++j) mt = fmaxf(mt, tv[j]);
        mt = fmaxf(mt, __shfl_xor(mt, 16));
        mt = fmaxf(mt, __shfl_xor(mt, 32));
        float mnew = fmaxf(m_r, mt);
        float p[16], rs = 0.0f;
#pragma unroll
        for (int j = 0; j < 16; ++j) { p[j] = __expf(tv[j] - mnew); rs += p[j]; }
        rs += __shfl_xor(rs, 16);
        rs += __shfl_xor(rs, 32);
        float alpha = __expf(m_r - mnew);
        l_r = l_r * alpha + rs;
        m_r = mnew;

        // P -> LDS (wave-private): row q=r, col kv = t*16 + quad*4 + i
#pragma unroll
        for (int t = 0; t < 4; ++t) {
            union { unsigned long long u; unsigned short s[4]; } pk;
#pragma unroll
            for (int i = 0; i < 4; ++i) pk.s[i] = bf16_bits(p[t * 4 + i]);
            *(unsigned long long*)&myP[r * 72 + t * 16 + quad * 4] = pk.u;
        }
        bf16x8 pf0 = *(const bf16x8*)&myP[r * 72 + quad * 8];
        bf16x8 pf1 = *(const bf16x8*)&myP[r * 72 + 32 + quad * 8];

        // V fragments from LDS (swizzled read)
        bf16x8 vf[4][2];
#pragma unroll
        for (int dt = 0; dt < 4; ++dt)
#pragma unroll
            for (int half = 0; half < 2; ++half)
                vf[dt][half] = *(const bf16x8*)&Vs[buf][(dt * 16 + r) * 64 + ((half * 4 + quad) ^ (r & 7)) * 8];

        // alpha for oacc rows q = quad*4+i lives in lane quad*4+i
        float ab[4];
#pragma unroll
        for (int i = 0; i < 4; ++i) ab[i] = __shfl(alpha, quad * 4 + i);

        __builtin_amdgcn_s_setprio(1);
#pragma unroll
        for (int dt = 0; dt < 4; ++dt) {
            f32x4 o = oacc[dt];
#pragma unroll
            for (int i = 0; i < 4; ++i) o[i] *= ab[i];
            o = __builtin_amdgcn_mfma_f32_16x16x32_bf16(pf0, vf[dt][0], o, 0, 0, 0);
            o = __builtin_amdgcn_mfma_f32_16x16x32_bf16(pf1, vf[dt][1], o, 0, 0, 0);
            oacc[dt] = o;
        }
        __builtin_amdgcn_s_setprio(0);

        __syncthreads();   // drain next-tile DMA (vmcnt 0) + all waves done with buf
    }

    float linv[4];
#pragma unroll
    for (int i = 0; i < 4; ++i) linv[i] = 1.0f / __shfl(l_r, quad * 4 + i);
#pragma unroll
    for (int dt = 0; dt < 4; ++dt)
#pragma unroll
        for (int i = 0; i < 4; ++i)
            Aout[(size_t)(b * S_LEN + q0 + quad * 4 + i) * 2048 + h * 64 + dt * 16 + r] =
                __float2bfloat16(oacc[dt][i] * linv[i]);
}

extern "C" void kernel_launch(void* const* d_in, const int* in_sizes, int n_in,
                              void* d_out, int out_size, void* d_ws, size_t ws_size,
                              hipStream_t stream) {
    const float* x  = (const float*)d_in[0];
    const float* wq = (const float*)d_in[1];
    const float* wk = (const float*)d_in[2];
    const float* wv = (const float*)d_in[3];
    const float* wo = (const float*)d_in[4];
    char* ws = (char*)d_ws;

    // d_out is 32 MB fp32. Park bf16 Q (16 MB) in its first half; the final
    // GEMM overwrites all of d_out with fp32 results afterwards.
    // ws (24 MB, phased):
    //   phase 1: [0,8M)=wqT [8,10M)=wkT [10,12M)=wvT
    //   phase 2: [0,16M)=attnOut(bf16)  [16,20M)=Kb  [20,24M)=Vt
    //   phase 3: [0,16M)=attnOut        [16,24M)=woT
    bf16* wqT  = (bf16*)(ws + 0);
    bf16* wkT  = (bf16*)(ws + 8388608);
    bf16* wvT  = (bf16*)(ws + 10485760);
    bf16* attn = (bf16*)(ws + 0);
    bf16* Kb   = (bf16*)(ws + 16777216);
    bf16* Vtb  = (bf16*)(ws + 20971520);
    bf16* woT  = (bf16*)(ws + 16777216);
    bf16* Qb   = (bf16*)d_out;

    transpose_k<<<dim3(64, 64), 256, 0, stream>>>(wq, wqT, 2048, 2048);
    transpose_k<<<dim3(16, 64), 256, 0, stream>>>(wk, wkT, 2048, 512);
    transpose_k<<<dim3(16, 64), 256, 0, stream>>>(wv, wvT, 2048, 512);

    gemm_k<<<dim3(16, 32), 256, 0, stream>>>(x, wqT, Qb, 4096, 2048, 2048, 0, 1);
    gemm_k<<<dim3(4, 32), 256, 0, stream>>>(x, wkT, Kb, 4096, 512, 2048, 0, 1);
    gemm_k<<<dim3(4, 32), 256, 0, stream>>>(x, wvT, Vtb, 4096, 512, 2048, 1, 1);

    attn_k<<<dim3(32, 32, 2), 256, 0, stream>>>(Qb, Kb, Vtb, attn);

    // Kb/Vt dead; put woT in their slot
    transpose_k<<<dim3(64, 64), 256, 0, stream>>>(wo, woT, 2048, 2048);

    // fp32 epilogue into d_out
    gemm_k<<<dim3(16, 32), 256, 0, stream>>>(attn, woT, d_out, 4096, 2048, 2048, 2, 0);
}

// Round 3
// 488.264 us; speedup vs baseline: 1.7414x; 1.1090x over previous
//
#include <hip/hip_runtime.h>
#include <hip/hip_bf16.h>

// Round 10: all GEMMs rebuilt to the m97 structure (global_load_lds staging,
// 128x128 tile, BK=32, linear LDS). x converted fp32->bf16 once via cvt_k
// (parked in d_out second half). attn_k unchanged from R9.

#define S_LEN 2048

typedef __hip_bfloat16 bf16;
using bf16x8 = __attribute__((ext_vector_type(8))) __bf16;
using f32x4  = __attribute__((ext_vector_type(4))) float;

__device__ inline unsigned short bf16_bits(float f) {
    union { __hip_bfloat16 h; unsigned short u; } cv;
    cv.h = __float2bfloat16(f);
    return cv.u;
}

__device__ inline float bits_to_f(unsigned short u) {
    union { __hip_bfloat16 h; unsigned short u; } cv;
    cv.u = u;
    return __bfloat162float(cv.h);
}

// load 8 consecutive fp32, convert RNE to a bf16x8 fragment
__device__ inline bf16x8 load_cvt8(const float* __restrict__ p) {
    f32x4 a = *(const f32x4*)p;
    f32x4 b = *(const f32x4*)(p + 4);
    union { bf16x8 v; unsigned short u[8]; } r;
    r.u[0] = bf16_bits(a[0]); r.u[1] = bf16_bits(a[1]);
    r.u[2] = bf16_bits(a[2]); r.u[3] = bf16_bits(a[3]);
    r.u[4] = bf16_bits(b[0]); r.u[5] = bf16_bits(b[1]);
    r.u[6] = bf16_bits(b[2]); r.u[7] = bf16_bits(b[3]);
    return r.v;
}

// async global->LDS, 16B per lane, dest = ldsbase + lane*16 (wave-uniform base)
__device__ inline void gload_lds16(const bf16* g, bf16* l) {
    __builtin_amdgcn_global_load_lds((const __attribute__((address_space(1))) void*)g,
                                     (__attribute__((address_space(3))) void*)l,
                                     16, 0, 0);
}

// ---------------- x fp32 -> bf16 (grid-stride, 8 elems/thread/iter) ----------
__global__ __launch_bounds__(256) void cvt_k(const float* __restrict__ in,
                                             bf16* __restrict__ out, int n8) {
    for (int i = blockIdx.x * 256 + threadIdx.x; i < n8; i += gridDim.x * 256)
        *(bf16x8*)(out + (size_t)i * 8) = load_cvt8(in + (size_t)i * 8);
}

// ---------------- weight transpose + fp32->bf16: out[n][k] = (bf16)in[k][n] ----
__global__ __launch_bounds__(256) void transpose_k(const float* __restrict__ in,
                                                   bf16* __restrict__ out,
                                                   int R, int C) {
    __shared__ float tile[32][33];
    int tx = threadIdx.x & 31, ty = threadIdx.x >> 5;  // ty 0..7
    int r0 = blockIdx.y * 32, c0 = blockIdx.x * 32;
#pragma unroll
    for (int p = 0; p < 4; ++p)
        tile[ty + p * 8][tx] = in[(size_t)(r0 + ty + p * 8) * C + c0 + tx];
    __syncthreads();
#pragma unroll
    for (int p = 0; p < 4; ++p)
        out[(size_t)(c0 + ty + p * 8) * R + r0 + tx] = __float2bfloat16(tile[tx][ty + p * 8]);
}

// ---------------- GEMM: C = A[M,K] * Bt[N,K]^T (bf16 MFMA, fp32 acc)
// m97 structure: global_load_lds staging, linear LDS [128][32], 2-barrier loop.
// mode 0: bf16 row-major C. mode 1: V-transpose epilogue into Vt[b][hkv][d][s].
// mode 2: fp32 row-major C.
__global__ __launch_bounds__(256) void gemm_k(const bf16* __restrict__ A,
                                              const bf16* __restrict__ Bt,
                                              void* __restrict__ Cv,
                                              int M, int N, int K, int mode) {
    __shared__ bf16 As[128 * 32];
    __shared__ bf16 Bs[128 * 32];
    int tid  = threadIdx.x;
    int lane = tid & 63, wave = tid >> 6;
    int quad = lane >> 4, r = lane & 15;
    int wm = (wave >> 1) * 64, wn = (wave & 1) * 64;
    int m0 = blockIdx.y * 128, n0 = blockIdx.x * 128;

    f32x4 acc[4][4];
#pragma unroll
    for (int i = 0; i < 4; ++i)
#pragma unroll
        for (int j = 0; j < 4; ++j) acc[i][j] = (f32x4)0.0f;

    int rg = lane >> 2;          // 0..15 row within 16-row group
    int ck = (lane & 3) << 3;    // 8-elem (16B) chunk within 32-col row

    for (int k0 = 0; k0 < K; k0 += 32) {
        // stage A and B tiles via async DMA: each wave fills 2x 16-row groups per matrix
#pragma unroll
        for (int g = 0; g < 2; ++g) {
            int grp = wave * 2 + g;              // 0..7
            int row = grp * 16 + rg;
            gload_lds16(A  + (size_t)(m0 + row) * K + k0 + ck, &As[grp * 512]);
            gload_lds16(Bt + (size_t)(n0 + row) * K + k0 + ck, &Bs[grp * 512]);
        }
        __syncthreads();   // drains vmcnt(0) then barrier: tile ready
        bf16x8 af[4], bfr[4];
#pragma unroll
        for (int mt = 0; mt < 4; ++mt) af[mt]  = *(const bf16x8*)&As[(wm + mt * 16 + r) * 32 + quad * 8];
#pragma unroll
        for (int nt = 0; nt < 4; ++nt) bfr[nt] = *(const bf16x8*)&Bs[(wn + nt * 16 + r) * 32 + quad * 8];
        __builtin_amdgcn_s_setprio(1);
#pragma unroll
        for (int mt = 0; mt < 4; ++mt)
#pragma unroll
            for (int nt = 0; nt < 4; ++nt)
                acc[mt][nt] = __builtin_amdgcn_mfma_f32_16x16x32_bf16(af[mt], bfr[nt], acc[mt][nt], 0, 0, 0);
        __builtin_amdgcn_s_setprio(0);
        __syncthreads();   // all reads done before next-step overwrite
    }

    if (mode == 0) {
        bf16* C = (bf16*)Cv;
#pragma unroll
        for (int mt = 0; mt < 4; ++mt)
#pragma unroll
            for (int nt = 0; nt < 4; ++nt) {
                int row = m0 + wm + mt * 16 + quad * 4;
                int col = n0 + wn + nt * 16 + r;
#pragma unroll
                for (int i = 0; i < 4; ++i)
                    C[(size_t)(row + i) * N + col] = __float2bfloat16(acc[mt][nt][i]);
            }
    } else if (mode == 1) {
        // Vt[b][hkv][d][s]: flat = (b*512 + col)*2048 + s ; 4 consecutive tokens per lane
        unsigned short* C = (unsigned short*)Cv;
#pragma unroll
        for (int mt = 0; mt < 4; ++mt)
#pragma unroll
            for (int nt = 0; nt < 4; ++nt) {
                int rowb = m0 + wm + mt * 16 + quad * 4;
                int col  = n0 + wn + nt * 16 + r;
                int b = rowb >> 11, s = rowb & 2047;
                ushort4 pk;
                pk.x = bf16_bits(acc[mt][nt][0]);
                pk.y = bf16_bits(acc[mt][nt][1]);
                pk.z = bf16_bits(acc[mt][nt][2]);
                pk.w = bf16_bits(acc[mt][nt][3]);
                *(ushort4*)(C + (size_t)(b * 512 + col) * 2048 + s) = pk;
            }
    } else {
        float* C = (float*)Cv;
#pragma unroll
        for (int mt = 0; mt < 4; ++mt)
#pragma unroll
            for (int nt = 0; nt < 4; ++nt) {
                int row = m0 + wm + mt * 16 + quad * 4;
                int col = n0 + wn + nt * 16 + r;
#pragma unroll
                for (int i = 0; i < 4; ++i)
                    C[(size_t)(row + i) * N + col] = acc[mt][nt][i];
            }
    }
}

// ---------------- flash attention (GQA), one (b, h, 64-row q-tile) per block
// LDS-staged K/V (double-buffered, global_load_lds DMA, XOR-chunk swizzle).
// Swapped QK^T: St = mfma(K, Q) -> lane owns q = lane&15, kv over regs/quads.
// Qin: [B,S,2048] bf16 (h*64+d), K: [B,S,512] bf16, Vt: [B][8][64][S] bf16
// Aout: [B,S,2048] bf16
__global__ __launch_bounds__(256) void attn_k(const bf16* __restrict__ Qin,
                                              const bf16* __restrict__ Kb,
                                              const bf16* __restrict__ Vt,
                                              bf16* __restrict__ Aout) {
    __shared__ bf16 Ks[2][64 * 64];   // [kv local][d], 16B chunks XOR-swizzled by row&7
    __shared__ bf16 Vs[2][64 * 64];   // [d][kv local], same swizzle
    __shared__ bf16 Pl[4][16 * 72];   // wave-private P round-trip

    int tid = threadIdx.x, lane = tid & 63, w = tid >> 6;
    int quad = lane >> 4, r = lane & 15;
    int qt = blockIdx.x, h = blockIdx.y, b = blockIdx.z;
    int hk = h >> 2;
    int q0 = qt * 64 + w * 16;

    // Q fragments, pre-scaled by 1/sqrt(64)=0.125 (exact in bf16)
    bf16x8 qf[2];
#pragma unroll
    for (int f = 0; f < 2; ++f) {
        bf16x8 v = *(const bf16x8*)(Qin + (size_t)(b * S_LEN + q0 + r) * 2048 + h * 64 + f * 32 + quad * 8);
        union { bf16x8 v; unsigned short u[8]; } in_, out_;
        in_.v = v;
#pragma unroll
        for (int j = 0; j < 8; ++j) out_.u[j] = bf16_bits(bits_to_f(in_.u[j]) * 0.125f);
        qf[f] = out_.v;
    }

    const bf16* Kbase = Kb + (size_t)b * S_LEN * 512 + hk * 64;
    const bf16* Vbase = Vt + (size_t)(b * 512 + hk * 64) * 2048;
    bf16* myP = &Pl[w][0];

    // staging geometry: each wave stages 16 K-rows and 16 V-rows (2+2 DMA ops)
    int srow   = lane >> 3;              // 0..7 row within 8-row group
    int schunk = (lane & 7) ^ srow;      // inverse-swizzled source chunk

    f32x4 oacc[4];
#pragma unroll
    for (int dt = 0; dt < 4; ++dt) oacc[dt] = (f32x4)0.0f;
    float m_r = -INFINITY, l_r = 0.0f;   // per-lane state for q = r (dup across quads)

    // prologue: stage tile 0
#pragma unroll
    for (int j = 0; j < 2; ++j) {
        int row = w * 16 + j * 8;
        gload_lds16(Kbase + (size_t)(row + srow) * 512 + schunk * 8, &Ks[0][row * 64]);
        gload_lds16(Vbase + (size_t)(row + srow) * 2048 + 0 + schunk * 8, &Vs[0][row * 64]);
    }
    __syncthreads();   // drains vmcnt + barrier

    for (int it = 0; it < S_LEN / 64; ++it) {
        int buf = it & 1;
        int k0n = (it + 1) * 64;
        if (k0n < S_LEN) {
#pragma unroll
            for (int j = 0; j < 2; ++j) {
                int row = w * 16 + j * 8;
                gload_lds16(Kbase + (size_t)(k0n + row + srow) * 512 + schunk * 8, &Ks[buf ^ 1][row * 64]);
                gload_lds16(Vbase + (size_t)(row + srow) * 2048 + k0n + schunk * 8, &Vs[buf ^ 1][row * 64]);
            }
        }

        // K fragments from LDS (swizzled read)
        bf16x8 kf[4][2];
#pragma unroll
        for (int t = 0; t < 4; ++t)
#pragma unroll
            for (int half = 0; half < 2; ++half)
                kf[t][half] = *(const bf16x8*)&Ks[buf][(t * 16 + r) * 64 + ((half * 4 + quad) ^ (r & 7)) * 8];

        f32x4 St[4];
        __builtin_amdgcn_s_setprio(1);
#pragma unroll
        for (int t = 0; t < 4; ++t) {
            St[t] = (f32x4)0.0f;
            St[t] = __builtin_amdgcn_mfma_f32_16x16x32_bf16(kf[t][0], qf[0], St[t], 0, 0, 0);
            St[t] = __builtin_amdgcn_mfma_f32_16x16x32_bf16(kf[t][1], qf[1], St[t], 0, 0, 0);
        }
        __builtin_amdgcn_s_setprio(0);

        // online softmax (Q pre-scaled): 16 kv values in-lane, 2 shuffles over quads
        float tv[16];
#pragma unroll
        for (int t = 0; t < 4; ++t)
#pragma unroll
            for (int i = 0; i < 4; ++i) tv[t * 4 + i] = St[t][i];
        float mt = tv[0];
#pragma unroll
        for (int j = 1; j < 16; ++j) mt = fmaxf(mt, tv[j]);
        mt = fmaxf(mt, __shfl_xor(mt, 16));
        mt = fmaxf(mt, __shfl_xor(mt, 32));
        float mnew = fmaxf(m_r, mt);
        float p[16], rs = 0.0f;
#pragma unroll
        for (int j = 0; j < 16; ++j) { p[j] = __expf(tv[j] - mnew); rs += p[j]; }
        rs += __shfl_xor(rs, 16);
        rs += __shfl_xor(rs, 32);
        float alpha = __expf(m_r - mnew);
        l_r = l_r * alpha + rs;
        m_r = mnew;

        // P -> LDS (wave-private): row q=r, col kv = t*16 + quad*4 + i
#pragma unroll
        for (int t = 0; t < 4; ++t) {
            union { unsigned long long u; unsigned short s[4]; } pk;
#pragma unroll
            for (int i = 0; i < 4; ++i) pk.s[i] = bf16_bits(p[t * 4 + i]);
            *(unsigned long long*)&myP[r * 72 + t * 16 + quad * 4] = pk.u;
        }
        bf16x8 pf0 = *(const bf16x8*)&myP[r * 72 + quad * 8];
        bf16x8 pf1 = *(const bf16x8*)&myP[r * 72 + 32 + quad * 8];

        // V fragments from LDS (swizzled read)
        bf16x8 vf[4][2];
#pragma unroll
        for (int dt = 0; dt < 4; ++dt)
#pragma unroll
            for (int half = 0; half < 2; ++half)
                vf[dt][half] = *(const bf16x8*)&Vs[buf][(dt * 16 + r) * 64 + ((half * 4 + quad) ^ (r & 7)) * 8];

        // alpha for oacc rows q = quad*4+i lives in lane quad*4+i
        float ab[4];
#pragma unroll
        for (int i = 0; i < 4; ++i) ab[i] = __shfl(alpha, quad * 4 + i);

        __builtin_amdgcn_s_setprio(1);
#pragma unroll
        for (int dt = 0; dt < 4; ++dt) {
            f32x4 o = oacc[dt];
#pragma unroll
            for (int i = 0; i < 4; ++i) o[i] *= ab[i];
            o = __builtin_amdgcn_mfma_f32_16x16x32_bf16(pf0, vf[dt][0], o, 0, 0, 0);
            o = __builtin_amdgcn_mfma_f32_16x16x32_bf16(pf1, vf[dt][1], o, 0, 0, 0);
            oacc[dt] = o;
        }
        __builtin_amdgcn_s_setprio(0);

        __syncthreads();   // drain next-tile DMA (vmcnt 0) + all waves done with buf
    }

    float linv[4];
#pragma unroll
    for (int i = 0; i < 4; ++i) linv[i] = 1.0f / __shfl(l_r, quad * 4 + i);
#pragma unroll
    for (int dt = 0; dt < 4; ++dt)
#pragma unroll
        for (int i = 0; i < 4; ++i)
            Aout[(size_t)(b * S_LEN + q0 + quad * 4 + i) * 2048 + h * 64 + dt * 16 + r] =
                __float2bfloat16(oacc[dt][i] * linv[i]);
}

extern "C" void kernel_launch(void* const* d_in, const int* in_sizes, int n_in,
                              void* d_out, int out_size, void* d_ws, size_t ws_size,
                              hipStream_t stream) {
    const float* x  = (const float*)d_in[0];
    const float* wq = (const float*)d_in[1];
    const float* wk = (const float*)d_in[2];
    const float* wv = (const float*)d_in[3];
    const float* wo = (const float*)d_in[4];
    char* ws = (char*)d_ws;

    // d_out is 32 MB fp32:
    //   [0,16M)  = Qb (bf16 Q projections)
    //   [16,32M) = xb (bf16 copy of x)
    // Both dead by the time the final GEMM overwrites d_out with fp32 output.
    // ws (24 MB, phased):
    //   phase 1: [0,8M)=wqT [8,10M)=wkT [10,12M)=wvT
    //   phase 2: [0,16M)=attnOut(bf16)  [16,20M)=Kb  [20,24M)=Vt
    //   phase 3: [0,16M)=attnOut        [16,24M)=woT
    bf16* wqT  = (bf16*)(ws + 0);
    bf16* wkT  = (bf16*)(ws + 8388608);
    bf16* wvT  = (bf16*)(ws + 10485760);
    bf16* attn = (bf16*)(ws + 0);
    bf16* Kb   = (bf16*)(ws + 16777216);
    bf16* Vtb  = (bf16*)(ws + 20971520);
    bf16* woT  = (bf16*)(ws + 16777216);
    bf16* Qb   = (bf16*)d_out;
    bf16* xb   = (bf16*)((char*)d_out + 16777216);

    cvt_k<<<dim3(2048), 256, 0, stream>>>(x, xb, (2 * S_LEN * 2048) / 8);
    transpose_k<<<dim3(64, 64), 256, 0, stream>>>(wq, wqT, 2048, 2048);
    transpose_k<<<dim3(16, 64), 256, 0, stream>>>(wk, wkT, 2048, 512);
    transpose_k<<<dim3(16, 64), 256, 0, stream>>>(wv, wvT, 2048, 512);

    gemm_k<<<dim3(16, 32), 256, 0, stream>>>(xb, wqT, Qb, 4096, 2048, 2048, 0);
    gemm_k<<<dim3(4, 32), 256, 0, stream>>>(xb, wkT, Kb, 4096, 512, 2048, 0);
    gemm_k<<<dim3(4, 32), 256, 0, stream>>>(xb, wvT, Vtb, 4096, 512, 2048, 1);

    attn_k<<<dim3(32, 32, 2), 256, 0, stream>>>(Qb, Kb, Vtb, attn);

    // Kb/Vt dead; put woT in their slot
    transpose_k<<<dim3(64, 64), 256, 0, stream>>>(wo, woT, 2048, 2048);

    // fp32 epilogue into d_out (Qb/xb dead)
    gemm_k<<<dim3(16, 32), 256, 0, stream>>>(attn, woT, d_out, 4096, 2048, 2048, 2);
}

// Round 4
// 404.777 us; speedup vs baseline: 2.1005x; 1.2063x over previous
//
#include <hip/hip_runtime.h>
#include <hip/hip_bf16.h>

// Round 11: (1) Q/K/V projections fused into ONE GEMM (N=3072, 768 blocks) with
// per-region epilogue; (2) attn_k LDS trimmed to exactly 40960 B (4 blocks/CU)
// via XOR-swizzled stride-64 P buffer; (3) bit-exact defer-max skip + max3 tree.

#define S_LEN 2048

typedef __hip_bfloat16 bf16;
using bf16x8 = __attribute__((ext_vector_type(8))) __bf16;
using f32x4  = __attribute__((ext_vector_type(4))) float;

__device__ inline unsigned short bf16_bits(float f) {
    union { __hip_bfloat16 h; unsigned short u; } cv;
    cv.h = __float2bfloat16(f);
    return cv.u;
}

__device__ inline float bits_to_f(unsigned short u) {
    union { __hip_bfloat16 h; unsigned short u; } cv;
    cv.u = u;
    return __bfloat162float(cv.h);
}

// load 8 consecutive fp32, convert RNE to a bf16x8 fragment
__device__ inline bf16x8 load_cvt8(const float* __restrict__ p) {
    f32x4 a = *(const f32x4*)p;
    f32x4 b = *(const f32x4*)(p + 4);
    union { bf16x8 v; unsigned short u[8]; } r;
    r.u[0] = bf16_bits(a[0]); r.u[1] = bf16_bits(a[1]);
    r.u[2] = bf16_bits(a[2]); r.u[3] = bf16_bits(a[3]);
    r.u[4] = bf16_bits(b[0]); r.u[5] = bf16_bits(b[1]);
    r.u[6] = bf16_bits(b[2]); r.u[7] = bf16_bits(b[3]);
    return r.v;
}

// async global->LDS, 16B per lane, dest = ldsbase + lane*16 (wave-uniform base)
__device__ inline void gload_lds16(const bf16* g, bf16* l) {
    __builtin_amdgcn_global_load_lds((const __attribute__((address_space(1))) void*)g,
                                     (__attribute__((address_space(3))) void*)l,
                                     16, 0, 0);
}

// ---------------- x fp32 -> bf16 (grid-stride, 8 elems/thread/iter) ----------
__global__ __launch_bounds__(256) void cvt_k(const float* __restrict__ in,
                                             bf16* __restrict__ out, int n8) {
    for (int i = blockIdx.x * 256 + threadIdx.x; i < n8; i += gridDim.x * 256)
        *(bf16x8*)(out + (size_t)i * 8) = load_cvt8(in + (size_t)i * 8);
}

// ---------------- weight transpose + fp32->bf16: out[n][k] = (bf16)in[k][n] ----
__global__ __launch_bounds__(256) void transpose_k(const float* __restrict__ in,
                                                   bf16* __restrict__ out,
                                                   int R, int C) {
    __shared__ float tile[32][33];
    int tx = threadIdx.x & 31, ty = threadIdx.x >> 5;  // ty 0..7
    int r0 = blockIdx.y * 32, c0 = blockIdx.x * 32;
#pragma unroll
    for (int p = 0; p < 4; ++p)
        tile[ty + p * 8][tx] = in[(size_t)(r0 + ty + p * 8) * C + c0 + tx];
    __syncthreads();
#pragma unroll
    for (int p = 0; p < 4; ++p)
        out[(size_t)(c0 + ty + p * 8) * R + r0 + tx] = __float2bfloat16(tile[tx][ty + p * 8]);
}

// ---------------- GEMM: C = A[M,K] * Bt[N,K]^T (bf16 MFMA, fp32 acc)
// m97 structure: global_load_lds staging, linear LDS [128][32], 2-barrier loop.
// mode 0: bf16 row-major C (stride N).
// mode 2: fp32 row-major C (stride N).
// mode 3: fused QKV epilogue: cols [0,2048)->Cv bf16 stride 2048,
//         [2048,2560)->Cv2 bf16 stride 512, [2560,3072)->Cv3 Vt scatter.
__global__ __launch_bounds__(256) void gemm_k(const bf16* __restrict__ A,
                                              const bf16* __restrict__ Bt,
                                              void* __restrict__ Cv,
                                              void* __restrict__ Cv2,
                                              void* __restrict__ Cv3,
                                              int M, int N, int K, int mode) {
    __shared__ bf16 As[128 * 32];
    __shared__ bf16 Bs[128 * 32];
    int tid  = threadIdx.x;
    int lane = tid & 63, wave = tid >> 6;
    int quad = lane >> 4, r = lane & 15;
    int wm = (wave >> 1) * 64, wn = (wave & 1) * 64;
    int m0 = blockIdx.y * 128, n0 = blockIdx.x * 128;

    f32x4 acc[4][4];
#pragma unroll
    for (int i = 0; i < 4; ++i)
#pragma unroll
        for (int j = 0; j < 4; ++j) acc[i][j] = (f32x4)0.0f;

    int rg = lane >> 2;          // 0..15 row within 16-row group
    int ck = (lane & 3) << 3;    // 8-elem (16B) chunk within 32-col row

    for (int k0 = 0; k0 < K; k0 += 32) {
        // stage A and B tiles via async DMA: each wave fills 2x 16-row groups per matrix
#pragma unroll
        for (int g = 0; g < 2; ++g) {
            int grp = wave * 2 + g;              // 0..7
            int row = grp * 16 + rg;
            gload_lds16(A  + (size_t)(m0 + row) * K + k0 + ck, &As[grp * 512]);
            gload_lds16(Bt + (size_t)(n0 + row) * K + k0 + ck, &Bs[grp * 512]);
        }
        __syncthreads();   // drains vmcnt(0) then barrier: tile ready
        bf16x8 af[4], bfr[4];
#pragma unroll
        for (int mt = 0; mt < 4; ++mt) af[mt]  = *(const bf16x8*)&As[(wm + mt * 16 + r) * 32 + quad * 8];
#pragma unroll
        for (int nt = 0; nt < 4; ++nt) bfr[nt] = *(const bf16x8*)&Bs[(wn + nt * 16 + r) * 32 + quad * 8];
        __builtin_amdgcn_s_setprio(1);
#pragma unroll
        for (int mt = 0; mt < 4; ++mt)
#pragma unroll
            for (int nt = 0; nt < 4; ++nt)
                acc[mt][nt] = __builtin_amdgcn_mfma_f32_16x16x32_bf16(af[mt], bfr[nt], acc[mt][nt], 0, 0, 0);
        __builtin_amdgcn_s_setprio(0);
        __syncthreads();   // all reads done before next-step overwrite
    }

    if (mode == 0) {
        bf16* C = (bf16*)Cv;
#pragma unroll
        for (int mt = 0; mt < 4; ++mt)
#pragma unroll
            for (int nt = 0; nt < 4; ++nt) {
                int row = m0 + wm + mt * 16 + quad * 4;
                int col = n0 + wn + nt * 16 + r;
#pragma unroll
                for (int i = 0; i < 4; ++i)
                    C[(size_t)(row + i) * N + col] = __float2bfloat16(acc[mt][nt][i]);
            }
    } else if (mode == 2) {
        float* C = (float*)Cv;
#pragma unroll
        for (int mt = 0; mt < 4; ++mt)
#pragma unroll
            for (int nt = 0; nt < 4; ++nt) {
                int row = m0 + wm + mt * 16 + quad * 4;
                int col = n0 + wn + nt * 16 + r;
#pragma unroll
                for (int i = 0; i < 4; ++i)
                    C[(size_t)(row + i) * N + col] = acc[mt][nt][i];
            }
    } else {
        // mode 3: fused QKV
        if (n0 < 2048) {
            bf16* C = (bf16*)Cv;          // Q: [4096][2048]
#pragma unroll
            for (int mt = 0; mt < 4; ++mt)
#pragma unroll
                for (int nt = 0; nt < 4; ++nt) {
                    int row = m0 + wm + mt * 16 + quad * 4;
                    int col = n0 + wn + nt * 16 + r;
#pragma unroll
                    for (int i = 0; i < 4; ++i)
                        C[(size_t)(row + i) * 2048 + col] = __float2bfloat16(acc[mt][nt][i]);
                }
        } else if (n0 < 2560) {
            bf16* C = (bf16*)Cv2;         // K: [4096][512]
#pragma unroll
            for (int mt = 0; mt < 4; ++mt)
#pragma unroll
                for (int nt = 0; nt < 4; ++nt) {
                    int row = m0 + wm + mt * 16 + quad * 4;
                    int col = n0 - 2048 + wn + nt * 16 + r;
#pragma unroll
                    for (int i = 0; i < 4; ++i)
                        C[(size_t)(row + i) * 512 + col] = __float2bfloat16(acc[mt][nt][i]);
                }
        } else {
            // V transpose: Vt[b][hkv][d][s]: flat = (b*512 + col)*2048 + s
            unsigned short* C = (unsigned short*)Cv3;
#pragma unroll
            for (int mt = 0; mt < 4; ++mt)
#pragma unroll
                for (int nt = 0; nt < 4; ++nt) {
                    int rowb = m0 + wm + mt * 16 + quad * 4;
                    int col  = n0 - 2560 + wn + nt * 16 + r;
                    int b = rowb >> 11, s = rowb & 2047;
                    ushort4 pk;
                    pk.x = bf16_bits(acc[mt][nt][0]);
                    pk.y = bf16_bits(acc[mt][nt][1]);
                    pk.z = bf16_bits(acc[mt][nt][2]);
                    pk.w = bf16_bits(acc[mt][nt][3]);
                    *(ushort4*)(C + (size_t)(b * 512 + col) * 2048 + s) = pk;
                }
        }
    }
}

// ---------------- flash attention (GQA), one (b, h, 64-row q-tile) per block
// LDS-staged K/V (double-buffered, global_load_lds DMA, XOR-chunk swizzle).
// Swapped QK^T: St = mfma(K, Q) -> lane owns q = lane&15, kv over regs/quads.
// LDS exactly 40960 B -> 4 blocks/CU. Bit-exact defer-max skip path.
// Qin: [B,S,2048] bf16 (h*64+d), K: [B,S,512] bf16, Vt: [B][8][64][S] bf16
// Aout: [B,S,2048] bf16
__global__ __launch_bounds__(256) void attn_k(const bf16* __restrict__ Qin,
                                              const bf16* __restrict__ Kb,
                                              const bf16* __restrict__ Vt,
                                              bf16* __restrict__ Aout) {
    __shared__ bf16 Ks[2][64 * 64];   // 16384 B: [kv][d], 16B chunks XOR-swizzled by row&7
    __shared__ bf16 Vs[2][64 * 64];   // 16384 B: [d][kv], same swizzle
    __shared__ bf16 Pl[4][16 * 64];   //  8192 B: wave-private P, stride 64, XOR-swizzled

    int tid = threadIdx.x, lane = tid & 63, w = tid >> 6;
    int quad = lane >> 4, r = lane & 15;
    int qt = blockIdx.x, h = blockIdx.y, b = blockIdx.z;
    int hk = h >> 2;
    int q0 = qt * 64 + w * 16;

    // Q fragments, pre-scaled by 1/sqrt(64)=0.125 (exact in bf16)
    bf16x8 qf[2];
#pragma unroll
    for (int f = 0; f < 2; ++f) {
        bf16x8 v = *(const bf16x8*)(Qin + (size_t)(b * S_LEN + q0 + r) * 2048 + h * 64 + f * 32 + quad * 8);
        union { bf16x8 v; unsigned short u[8]; } in_, out_;
        in_.v = v;
#pragma unroll
        for (int j = 0; j < 8; ++j) out_.u[j] = bf16_bits(bits_to_f(in_.u[j]) * 0.125f);
        qf[f] = out_.v;
    }

    const bf16* Kbase = Kb + (size_t)b * S_LEN * 512 + hk * 64;
    const bf16* Vbase = Vt + (size_t)(b * 512 + hk * 64) * 2048;
    char* myP = (char*)&Pl[w][0];

    // staging geometry: each wave stages 16 K-rows and 16 V-rows (2+2 DMA ops)
    int srow   = lane >> 3;              // 0..7 row within 8-row group
    int schunk = (lane & 7) ^ srow;      // inverse-swizzled source chunk

    f32x4 oacc[4];
#pragma unroll
    for (int dt = 0; dt < 4; ++dt) oacc[dt] = (f32x4)0.0f;
    float m_r = -INFINITY, l_r = 0.0f;   // per-lane state for q = r (dup across quads)

    // prologue: stage tile 0
#pragma unroll
    for (int j = 0; j < 2; ++j) {
        int row = w * 16 + j * 8;
        gload_lds16(Kbase + (size_t)(row + srow) * 512 + schunk * 8, &Ks[0][row * 64]);
        gload_lds16(Vbase + (size_t)(row + srow) * 2048 + 0 + schunk * 8, &Vs[0][row * 64]);
    }
    __syncthreads();   // drains vmcnt + barrier

    for (int it = 0; it < S_LEN / 64; ++it) {
        int buf = it & 1;
        int k0n = (it + 1) * 64;
        if (k0n < S_LEN) {
#pragma unroll
            for (int j = 0; j < 2; ++j) {
                int row = w * 16 + j * 8;
                gload_lds16(Kbase + (size_t)(k0n + row + srow) * 512 + schunk * 8, &Ks[buf ^ 1][row * 64]);
                gload_lds16(Vbase + (size_t)(row + srow) * 2048 + k0n + schunk * 8, &Vs[buf ^ 1][row * 64]);
            }
        }

        // K fragments from LDS (swizzled read)
        bf16x8 kf[4][2];
#pragma unroll
        for (int t = 0; t < 4; ++t)
#pragma unroll
            for (int half = 0; half < 2; ++half)
                kf[t][half] = *(const bf16x8*)&Ks[buf][(t * 16 + r) * 64 + ((half * 4 + quad) ^ (r & 7)) * 8];

        f32x4 St[4];
        __builtin_amdgcn_s_setprio(1);
#pragma unroll
        for (int t = 0; t < 4; ++t) {
            St[t] = (f32x4)0.0f;
            St[t] = __builtin_amdgcn_mfma_f32_16x16x32_bf16(kf[t][0], qf[0], St[t], 0, 0, 0);
            St[t] = __builtin_amdgcn_mfma_f32_16x16x32_bf16(kf[t][1], qf[1], St[t], 0, 0, 0);
        }
        __builtin_amdgcn_s_setprio(0);

        // online softmax (Q pre-scaled): 16 kv values in-lane, 2 shuffles over quads
        float tv[16];
#pragma unroll
        for (int t = 0; t < 4; ++t)
#pragma unroll
            for (int i = 0; i < 4; ++i) tv[t * 4 + i] = St[t][i];
        // max3-friendly tree (clang fuses nested fmaxf into v_max3)
        float a0 = fmaxf(fmaxf(tv[0], tv[1]), tv[2]);
        float a1 = fmaxf(fmaxf(tv[3], tv[4]), tv[5]);
        float a2 = fmaxf(fmaxf(tv[6], tv[7]), tv[8]);
        float a3 = fmaxf(fmaxf(tv[9], tv[10]), tv[11]);
        float a4 = fmaxf(fmaxf(tv[12], tv[13]), tv[14]);
        float mt = fmaxf(fmaxf(fmaxf(a0, a1), a2), fmaxf(fmaxf(a3, a4), tv[15]));
        mt = fmaxf(mt, __shfl_xor(mt, 16));
        mt = fmaxf(mt, __shfl_xor(mt, 32));

        int grow = __any(mt > m_r);
        float mnew = grow ? fmaxf(m_r, mt) : m_r;   // if !grow this is exactly m_r

        float p[16], rs = 0.0f;
#pragma unroll
        for (int j = 0; j < 16; ++j) { p[j] = __expf(tv[j] - mnew); rs += p[j]; }
        rs += __shfl_xor(rs, 16);
        rs += __shfl_xor(rs, 32);

        // P -> LDS (wave-private, stride 64, chunk-XOR swizzle by r&7)
#pragma unroll
        for (int t = 0; t < 4; ++t) {
            union { unsigned long long u; unsigned short s[4]; } pk;
#pragma unroll
            for (int i = 0; i < 4; ++i) pk.s[i] = bf16_bits(p[t * 4 + i]);
            *(unsigned long long*)(myP + r * 128 + (((t * 2 + (quad >> 1)) ^ (r & 7)) * 16) + (quad & 1) * 8) = pk.u;
        }
        bf16x8 pf0 = *(const bf16x8*)(myP + r * 128 + ((quad ^ (r & 7)) * 16));
        bf16x8 pf1 = *(const bf16x8*)(myP + r * 128 + (((4 + quad) ^ (r & 7)) * 16));

        // V fragments from LDS (swizzled read)
        bf16x8 vf[4][2];
#pragma unroll
        for (int dt = 0; dt < 4; ++dt)
#pragma unroll
            for (int half = 0; half < 2; ++half)
                vf[dt][half] = *(const bf16x8*)&Vs[buf][(dt * 16 + r) * 64 + ((half * 4 + quad) ^ (r & 7)) * 8];

        if (grow) {
            float alpha = __expf(m_r - mnew);
            l_r = l_r * alpha + rs;
            m_r = mnew;
            float ab[4];
#pragma unroll
            for (int i = 0; i < 4; ++i) ab[i] = __shfl(alpha, quad * 4 + i);
            __builtin_amdgcn_s_setprio(1);
#pragma unroll
            for (int dt = 0; dt < 4; ++dt) {
                f32x4 o = oacc[dt];
#pragma unroll
                for (int i = 0; i < 4; ++i) o[i] *= ab[i];
                o = __builtin_amdgcn_mfma_f32_16x16x32_bf16(pf0, vf[dt][0], o, 0, 0, 0);
                o = __builtin_amdgcn_mfma_f32_16x16x32_bf16(pf1, vf[dt][1], o, 0, 0, 0);
                oacc[dt] = o;
            }
            __builtin_amdgcn_s_setprio(0);
        } else {
            // max unchanged: alpha == 1 exactly, skip rescale entirely (bit-exact)
            l_r += rs;
            __builtin_amdgcn_s_setprio(1);
#pragma unroll
            for (int dt = 0; dt < 4; ++dt) {
                f32x4 o = oacc[dt];
                o = __builtin_amdgcn_mfma_f32_16x16x32_bf16(pf0, vf[dt][0], o, 0, 0, 0);
                o = __builtin_amdgcn_mfma_f32_16x16x32_bf16(pf1, vf[dt][1], o, 0, 0, 0);
                oacc[dt] = o;
            }
            __builtin_amdgcn_s_setprio(0);
        }

        __syncthreads();   // drain next-tile DMA (vmcnt 0) + all waves done with buf
    }

    float linv[4];
#pragma unroll
    for (int i = 0; i < 4; ++i) linv[i] = 1.0f / __shfl(l_r, quad * 4 + i);
#pragma unroll
    for (int dt = 0; dt < 4; ++dt)
#pragma unroll
        for (int i = 0; i < 4; ++i)
            Aout[(size_t)(b * S_LEN + q0 + quad * 4 + i) * 2048 + h * 64 + dt * 16 + r] =
                __float2bfloat16(oacc[dt][i] * linv[i]);
}

extern "C" void kernel_launch(void* const* d_in, const int* in_sizes, int n_in,
                              void* d_out, int out_size, void* d_ws, size_t ws_size,
                              hipStream_t stream) {
    const float* x  = (const float*)d_in[0];
    const float* wq = (const float*)d_in[1];
    const float* wk = (const float*)d_in[2];
    const float* wv = (const float*)d_in[3];
    const float* wo = (const float*)d_in[4];
    char* ws = (char*)d_ws;

    // d_out is 32 MB fp32:
    //   [0,16M)  = Qb (bf16 Q projections)
    //   [16,32M) = xb (bf16 copy of x)
    // Both dead by the time the final GEMM overwrites d_out with fp32 output.
    // ws (24 MB, phased):
    //   phase 1: [0,12M) = wqkvT, a contiguous [3072][2048] bf16:
    //            rows 0..2047=wq^T, 2048..2559=wk^T, 2560..3071=wv^T
    //   phase 2: [0,16M)=attnOut(bf16)  [16,20M)=Kb  [20,24M)=Vt
    //   phase 3: [0,16M)=attnOut        [16,24M)=woT
    bf16* wqT  = (bf16*)(ws + 0);
    bf16* wkT  = (bf16*)(ws + 8388608);
    bf16* wvT  = (bf16*)(ws + 10485760);
    bf16* attn = (bf16*)(ws + 0);
    bf16* Kb   = (bf16*)(ws + 16777216);
    bf16* Vtb  = (bf16*)(ws + 20971520);
    bf16* woT  = (bf16*)(ws + 16777216);
    bf16* Qb   = (bf16*)d_out;
    bf16* xb   = (bf16*)((char*)d_out + 16777216);

    cvt_k<<<dim3(2048), 256, 0, stream>>>(x, xb, (2 * S_LEN * 2048) / 8);
    transpose_k<<<dim3(64, 64), 256, 0, stream>>>(wq, wqT, 2048, 2048);
    transpose_k<<<dim3(16, 64), 256, 0, stream>>>(wk, wkT, 2048, 512);
    transpose_k<<<dim3(16, 64), 256, 0, stream>>>(wv, wvT, 2048, 512);

    // fused QKV projection: 768 blocks, per-region epilogue
    gemm_k<<<dim3(24, 32), 256, 0, stream>>>(xb, wqT, Qb, Kb, Vtb, 4096, 3072, 2048, 3);

    attn_k<<<dim3(32, 32, 2), 256, 0, stream>>>(Qb, Kb, Vtb, attn);

    // Kb/Vt dead; put woT in their slot
    transpose_k<<<dim3(64, 64), 256, 0, stream>>>(wo, woT, 2048, 2048);

    // fp32 epilogue into d_out (Qb/xb dead)
    gemm_k<<<dim3(16, 32), 256, 0, stream>>>(attn, woT, d_out, nullptr, nullptr, 4096, 2048, 2048, 2);
}